// Round 8
// baseline (496.201 us; speedup 1.0000x reference)
//
#include <hip/hip_runtime.h>

typedef __attribute__((ext_vector_type(8))) short short8;
typedef __attribute__((ext_vector_type(4))) float f32x4;
typedef __attribute__((ext_vector_type(4))) unsigned int u32x4;   // native vec for nontemporal builtins

#define NN 8192
#define DD 64

// f32 -> bf16 RNE (internal y staging only)
__device__ inline unsigned short f2bf(float f){
  unsigned b = __float_as_uint(f);
  b = (b + 0x7fffu + ((b >> 16) & 1u)) >> 16;
  return (unsigned short)b;
}

// ---------------------------------------------------------------------------
// Confirmed: inputs f32, output f32, absmax 0.5 vs threshold 1.78.
// Algebra: softmax rows sum to 1 -> attn_agg == aggregated; Wa_* unused.
//   out = x@(Wobj+Wskip) + r@Wrel + A^T @ (x@Wnobj + bnobj) + (bobj+brel+bskip)
// A is exactly 0/1 -> f32->bf16 truncation EXACT -> bf16 MFMA for A^T y.
//
// R8: consolidation. R3/R4/R5/R7 (409.7/416.2/414.5/407.2) proved dur_us =
// ~330us fixed harness restore/poison (1GiB ws fill alone measured 160us)
// + ~77us kernels, and that contended f32 atomics are ~free (R3 vs R4).
// So: drop part planes AND accT AND k_out -- k_proj writes the dense term
// directly to d_out (covers every element once, fixes 0xAA poison), k_spmm
// atomicAdds A^T y straight into d_out. -72MB traffic, -1 launch.
// ---------------------------------------------------------------------------

// Kernel 1: out[i][d] = x@(Wobj+Wskip) + r@Wrel + (bobj+brel+bskip)  (direct)
//           yT[d][i]  = bf16( x@Wnobj + bnobj )
__global__ __launch_bounds__(256) void k_proj(
    const float* __restrict__ x, const float* __restrict__ r,
    const float* __restrict__ Wobj,  const float* __restrict__ bobj,
    const float* __restrict__ Wnobj, const float* __restrict__ bnobj,
    const float* __restrict__ Wrel,  const float* __restrict__ brel,
    const float* __restrict__ Wskip, const float* __restrict__ bskip,
    float* __restrict__ out, unsigned short* __restrict__ yT)
{
  const int i  = blockIdx.x * 256 + threadIdx.x;   // row
  const int d0 = blockIdx.y * 4;                   // 4 output dims

  float ay[4] = {0.f,0.f,0.f,0.f}, az[4] = {0.f,0.f,0.f,0.f};
  const float4* xp = (const float4*)(x + (size_t)i * DD);
  const float4* rp = (const float4*)(r + (size_t)i * DD);

#pragma unroll
  for (int kb = 0; kb < 4; kb++){                  // 16 k per chunk
    float xv[16], rv[16];
#pragma unroll
    for (int p = 0; p < 4; p++){
      float4 u = xp[kb*4 + p];
      xv[4*p+0]=u.x; xv[4*p+1]=u.y; xv[4*p+2]=u.z; xv[4*p+3]=u.w;
      float4 v = rp[kb*4 + p];
      rv[4*p+0]=v.x; rv[4*p+1]=v.y; rv[4*p+2]=v.z; rv[4*p+3]=v.w;
    }
#pragma unroll
    for (int kk = 0; kk < 16; kk++){
      const int wb = (kb*16 + kk) * DD + d0;       // uniform -> s_loads
      const float xk = xv[kk], rk = rv[kk];
#pragma unroll
      for (int t = 0; t < 4; t++){
        ay[t] += xk * Wnobj[wb + t];
        az[t] += xk * Wobj [wb + t];
        az[t] += xk * Wskip[wb + t];
        az[t] += rk * Wrel [wb + t];
      }
    }
  }

#pragma unroll
  for (int t = 0; t < 4; t++){
    ay[t] += bnobj[d0 + t];
    az[t] += bobj[d0 + t] + brel[d0 + t] + bskip[d0 + t];
    yT[(size_t)(d0 + t) * NN + i] = f2bf(ay[t]);   // coalesced along i
  }
  // 4 consecutive floats -> one dwordx4 store per thread (initializes d_out,
  // overwriting the harness's 0xAA poison before k_spmm's atomics land)
  *(float4*)(out + (size_t)i * DD + d0) = make_float4(az[0], az[1], az[2], az[3]);
}

// ---------------------------------------------------------------------------
// Kernel 2: out[j][d] += sum_k yT[d][k] * A[k][j]   (bf16 MFMA, f32 atomics)
// BN=256 (1KB A segments), 32-k tiles, double-buffered, KSPLIT=16.
// grid (32 jb, 16 kb) = 512 blocks = 2/CU. Atomics measured ~free (R3 vs R4).
// XOR-chunk swizzle: B-frag u16 reads and all staging phases <=2-way (free).
// ---------------------------------------------------------------------------
#define BN 256
#define KSPLIT 16
#define KCH (NN / KSPLIT)    // 512
#define KT 32                // k-depth per tile
#define NIT (KCH / KT)       // 16
#define ASZ (KT * BN)        // 8192 elems (16 KB)
#define YPITCH 40            // 32 + 8: rows 80B, 16B-aligned, af reads 2-way
#define YSZ (DD * YPITCH)    // 2560 elems (5 KB)

__global__ __launch_bounds__(256) void k_spmm(
    const float* __restrict__ A,
    const unsigned short* __restrict__ yT,
    float* __restrict__ out)
{
  __shared__ short Alds[2 * ASZ];
  __shared__ short Ylds[2 * YSZ];

  const int tid  = threadIdx.x;
  const int lane = tid & 63;
  const int wave = tid >> 6;
  const int q    = lane >> 4;    // k-quad within fragment
  const int nn   = lane & 15;    // m (A-frag) / n (B-frag, C col) index

  const int j0     = blockIdx.x * BN;
  const int kstart = blockIdx.y * KCH;

  // A staging: rows kr + 4p (p=0..7), cols c4*4 (16B)
  const int c4 = tid & 63;
  const int kr = tid >> 6;
  // y staging: 64 m-rows x 4 8-k chunks
  const int cY = tid & 3;
  const int m  = tid >> 2;

  const float* ap          = A  + (size_t)(kstart + kr) * NN + j0 + c4 * 4;
  const unsigned short* yp = yT + (size_t)m * NN + kstart + cY * 8;

  u32x4 abuf[8]; uint4 ybuf;
  auto gload = [&](){
#pragma unroll
    for (int p = 0; p < 8; p++)   // nontemporal: A lines are single-use
      abuf[p] = __builtin_nontemporal_load((const u32x4*)(ap + (size_t)p * 4 * NN));
    ybuf = *(const uint4*)yp;
    ap += (size_t)KT * NN;
    yp += KT;
  };
  auto stage = [&](int buf){
    short* Ab = &Alds[buf * ASZ];
    short* Yb = &Ylds[buf * YSZ];
#pragma unroll
    for (int p = 0; p < 8; p++){
      const int kk  = kr + p*4;                    // 0..31
      const int key = 2 * ((kk >> 3) & 3);
      // exact f32->bf16 truncation (A is 0/1), packed two at a time
      unsigned lo = (abuf[p][1] & 0xFFFF0000u) | (abuf[p][0] >> 16);
      unsigned hi = (abuf[p][3] & 0xFFFF0000u) | (abuf[p][2] >> 16);
      *(uint2*)(&Ab[kk * BN + (((c4 >> 1) ^ key) * 8) + (c4 & 1) * 4]) =
          make_uint2(lo, hi);
    }
    *(uint4*)(&Yb[m * YPITCH + cY * 8]) = ybuf;
  };

  f32x4 acc[4][4];
#pragma unroll
  for (int a = 0; a < 4; a++)
#pragma unroll
    for (int b = 0; b < 4; b++)
      acc[a][b] = (f32x4){0.f, 0.f, 0.f, 0.f};

  gload();
  stage(0);
  __syncthreads();

  for (int it = 0; it < NIT; ++it){
    if (it + 1 < NIT) gload();       // in flight across this tile's compute
    const short* Ab = &Alds[(it & 1) * ASZ];
    const short* Yb = &Ylds[(it & 1) * YSZ];

    short8 af[4];
#pragma unroll
    for (int mt = 0; mt < 4; mt++)    // A-frag: yT[m=16mt+nn][k=q*8..q*8+7]
      af[mt] = *(const short8*)(&Yb[(mt*16 + nn) * YPITCH + q*8]);
#pragma unroll
    for (int nt = 0; nt < 4; nt++){
      const int col = wave * 64 + nt * 16 + nn;
      // B-frag: A[k=q*8+jj][col]; chunk swizzle key (k>>3)&3 == q for jj<8
      const short* bp = &Ab[(q*8) * BN + (((col >> 3) ^ (2*q)) * 8) + (col & 7)];
      short8 bf;
#pragma unroll
      for (int jj = 0; jj < 8; jj++) bf[jj] = bp[jj * BN];
#pragma unroll
      for (int mt = 0; mt < 4; mt++)
        acc[mt][nt] = __builtin_amdgcn_mfma_f32_16x16x32_bf16(af[mt], bf, acc[mt][nt], 0, 0, 0);
    }

    if (it + 1 < NIT){
      stage((it + 1) & 1);   // other buffer: safe, all waves passed barrier it-1
      __syncthreads();       // buf (it+1) complete before anyone computes it
    }
  }

  // epilogue: C/D layout col=lane&15, row=q*4+reg. Straight into d_out[j][d];
  // k_proj already initialized every element (stream-serialized before us).
#pragma unroll
  for (int mt = 0; mt < 4; mt++)
#pragma unroll
    for (int nt = 0; nt < 4; nt++){
      const int col = j0 + wave * 64 + nt * 16 + nn;
#pragma unroll
      for (int v = 0; v < 4; v++){
        const int d = mt * 16 + q * 4 + v;
        atomicAdd(out + (size_t)col * DD + d, acc[mt][nt][v]);
      }
    }
}

extern "C" void kernel_launch(void* const* d_in, const int* in_sizes, int n_in,
                              void* d_out, int out_size, void* d_ws, size_t ws_size,
                              hipStream_t stream) {
  const float* x     = (const float*)d_in[0];
  const float* r     = (const float*)d_in[1];
  const float* A     = (const float*)d_in[2];
  const float* Wobj  = (const float*)d_in[3];
  const float* bobj  = (const float*)d_in[4];
  const float* Wnobj = (const float*)d_in[5];
  const float* bnobj = (const float*)d_in[6];
  const float* Wrel  = (const float*)d_in[7];
  const float* brel  = (const float*)d_in[8];
  const float* Wskip = (const float*)d_in[9];
  const float* bskip = (const float*)d_in[10];
  // d_in[11]/d_in[12] (Wa_w/Wa_b) provably unused: softmax rows sum to 1.

  unsigned short* yT = (unsigned short*)d_ws;     // 1 MB; only ws use now

  k_proj<<<dim3(32, 16), 256, 0, stream>>>(x, r, Wobj, bobj, Wnobj, bnobj,
                                           Wrel, brel, Wskip, bskip,
                                           (float*)d_out, yT);
  k_spmm<<<dim3(NN / BN, KSPLIT), 256, 0, stream>>>(A, yT, (float*)d_out);
}

// Round 9
// 419.188 us; speedup vs baseline: 1.1837x; 1.1837x over previous
//
#include <hip/hip_runtime.h>

typedef __attribute__((ext_vector_type(8))) short short8;
typedef __attribute__((ext_vector_type(4))) float f32x4;
typedef __attribute__((ext_vector_type(4))) unsigned int u32x4;   // native vec for nontemporal builtins

#define NN 8192
#define DD 64

// f32 -> bf16 RNE (internal y staging only)
__device__ inline unsigned short f2bf(float f){
  unsigned b = __float_as_uint(f);
  b = (b + 0x7fffu + ((b >> 16) & 1u)) >> 16;
  return (unsigned short)b;
}

// ---------------------------------------------------------------------------
// Confirmed: inputs f32, output f32, absmax 0.5 vs threshold 1.78.
// Algebra: softmax rows sum to 1 -> attn_agg == aggregated; Wa_* unused.
//   out = x@(Wobj+Wskip) + r@Wrel + A^T @ (x@Wnobj + bnobj) + (bobj+brel+bskip)
// A is exactly 0/1 -> f32->bf16 truncation EXACT -> bf16 MFMA for A^T y.
//
// Atomic law (R3 vs R4 vs R8): f32 atomics are ~free when each instruction's
// 16 active lanes cover a contiguous 64B segment (R3); scattered stride-256B
// atomics cost ~+90us for 8.4M (R8). R9 keeps R8's consolidation (no accT,
// no part planes, no k_out) but SWAPS the MFMA operands: A-matrix tile as
// M-side (rows=j), y as N-side (cols=d) -> C/D epilogue addresses are
// j-row-major with d contiguous across lanes = coalesced 64B atomic segments
// straight into d_out. Both fragment lane-maps already validated in R3-R8.
// ---------------------------------------------------------------------------

// Kernel 1: out[i][d] = x@(Wobj+Wskip) + r@Wrel + (bobj+brel+bskip)  (direct)
//           yT[d][i]  = bf16( x@Wnobj + bnobj )
__global__ __launch_bounds__(256) void k_proj(
    const float* __restrict__ x, const float* __restrict__ r,
    const float* __restrict__ Wobj,  const float* __restrict__ bobj,
    const float* __restrict__ Wnobj, const float* __restrict__ bnobj,
    const float* __restrict__ Wrel,  const float* __restrict__ brel,
    const float* __restrict__ Wskip, const float* __restrict__ bskip,
    float* __restrict__ out, unsigned short* __restrict__ yT)
{
  const int i  = blockIdx.x * 256 + threadIdx.x;   // row
  const int d0 = blockIdx.y * 4;                   // 4 output dims

  float ay[4] = {0.f,0.f,0.f,0.f}, az[4] = {0.f,0.f,0.f,0.f};
  const float4* xp = (const float4*)(x + (size_t)i * DD);
  const float4* rp = (const float4*)(r + (size_t)i * DD);

#pragma unroll
  for (int kb = 0; kb < 4; kb++){                  // 16 k per chunk
    float xv[16], rv[16];
#pragma unroll
    for (int p = 0; p < 4; p++){
      float4 u = xp[kb*4 + p];
      xv[4*p+0]=u.x; xv[4*p+1]=u.y; xv[4*p+2]=u.z; xv[4*p+3]=u.w;
      float4 v = rp[kb*4 + p];
      rv[4*p+0]=v.x; rv[4*p+1]=v.y; rv[4*p+2]=v.z; rv[4*p+3]=v.w;
    }
#pragma unroll
    for (int kk = 0; kk < 16; kk++){
      const int wb = (kb*16 + kk) * DD + d0;       // uniform -> s_loads
      const float xk = xv[kk], rk = rv[kk];
#pragma unroll
      for (int t = 0; t < 4; t++){
        ay[t] += xk * Wnobj[wb + t];
        az[t] += xk * Wobj [wb + t];
        az[t] += xk * Wskip[wb + t];
        az[t] += rk * Wrel [wb + t];
      }
    }
  }

#pragma unroll
  for (int t = 0; t < 4; t++){
    ay[t] += bnobj[d0 + t];
    az[t] += bobj[d0 + t] + brel[d0 + t] + bskip[d0 + t];
    yT[(size_t)(d0 + t) * NN + i] = f2bf(ay[t]);   // coalesced along i
  }
  // initializes d_out (overwrites 0xAA poison) before k_spmm's atomics
  *(float4*)(out + (size_t)i * DD + d0) = make_float4(az[0], az[1], az[2], az[3]);
}

// ---------------------------------------------------------------------------
// Kernel 2: out[j][d] += sum_k A[k][j] * y[k][d]   (bf16 MFMA, f32 atomics)
// Operand-swapped: A^T tile is the M-side (rows=j), y the N-side (cols=d).
// BN=256 j's/block, KT=32-k tiles, double-buffered, KSPLIT=16, grid (32,16).
// Epilogue: coalesced 64B atomic segments straight into d_out.
// ---------------------------------------------------------------------------
#define BN 256
#define KSPLIT 16
#define KCH (NN / KSPLIT)    // 512
#define KT 32                // k-depth per tile
#define NIT (KCH / KT)       // 16
#define ASZ (KT * BN)        // 8192 elems (16 KB)
#define YPITCH 40            // rows 80B, 16B-aligned staging
#define YSZ (DD * YPITCH)    // 2560 elems (5 KB)

__global__ __launch_bounds__(256) void k_spmm(
    const float* __restrict__ A,
    const unsigned short* __restrict__ yT,
    float* __restrict__ out)
{
  __shared__ short Alds[2 * ASZ];
  __shared__ short Ylds[2 * YSZ];

  const int tid  = threadIdx.x;
  const int lane = tid & 63;
  const int wave = tid >> 6;
  const int q    = lane >> 4;    // k-quad within fragment
  const int nn   = lane & 15;    // m (A^T-frag j) / n (y-frag d, C col) index

  const int j0     = blockIdx.x * BN;
  const int kstart = blockIdx.y * KCH;

  // A staging: rows kr + 4p (p=0..7), cols c4*4 (16B)
  const int c4 = tid & 63;
  const int kr = tid >> 6;
  // y staging: 64 d-rows x 4 8-k chunks
  const int cY = tid & 3;
  const int m  = tid >> 2;

  const float* ap          = A  + (size_t)(kstart + kr) * NN + j0 + c4 * 4;
  const unsigned short* yp = yT + (size_t)m * NN + kstart + cY * 8;

  u32x4 abuf[8]; uint4 ybuf;
  auto gload = [&](){
#pragma unroll
    for (int p = 0; p < 8; p++)   // nontemporal: A lines are single-use
      abuf[p] = __builtin_nontemporal_load((const u32x4*)(ap + (size_t)p * 4 * NN));
    ybuf = *(const uint4*)yp;
    ap += (size_t)KT * NN;
    yp += KT;
  };
  auto stage = [&](int buf){
    short* Ab = &Alds[buf * ASZ];
    short* Yb = &Ylds[buf * YSZ];
#pragma unroll
    for (int p = 0; p < 8; p++){
      const int kk  = kr + p*4;                    // 0..31
      const int key = 2 * ((kk >> 3) & 3);
      // exact f32->bf16 truncation (A is 0/1), packed two at a time
      unsigned lo = (abuf[p][1] & 0xFFFF0000u) | (abuf[p][0] >> 16);
      unsigned hi = (abuf[p][3] & 0xFFFF0000u) | (abuf[p][2] >> 16);
      *(uint2*)(&Ab[kk * BN + (((c4 >> 1) ^ key) * 8) + (c4 & 1) * 4]) =
          make_uint2(lo, hi);
    }
    *(uint4*)(&Yb[m * YPITCH + cY * 8]) = ybuf;
  };

  f32x4 acc[4][4];
#pragma unroll
  for (int a = 0; a < 4; a++)
#pragma unroll
    for (int b = 0; b < 4; b++)
      acc[a][b] = (f32x4){0.f, 0.f, 0.f, 0.f};

  gload();
  stage(0);
  __syncthreads();

  for (int it = 0; it < NIT; ++it){
    if (it + 1 < NIT) gload();       // in flight across this tile's compute
    const short* Ab = &Alds[(it & 1) * ASZ];
    const short* Yb = &Ylds[(it & 1) * YSZ];

    short8 yf[4];
#pragma unroll
    for (int nt = 0; nt < 4; nt++)    // B-frag: y[k=q*8+jj][d=nt*16+nn]
      yf[nt] = *(const short8*)(&Yb[(nt*16 + nn) * YPITCH + q*8]);
#pragma unroll
    for (int mt = 0; mt < 4; mt++){
      const int jcol = wave * 64 + mt * 16 + nn;
      // A^T-frag: A[k=q*8+jj][jcol]; chunk swizzle key (k>>3)&3 == q for jj<8
      const short* apos = &Ab[(q*8) * BN + (((jcol >> 3) ^ (2*q)) * 8) + (jcol & 7)];
      short8 ajf;
#pragma unroll
      for (int jj = 0; jj < 8; jj++) ajf[jj] = apos[jj * BN];
#pragma unroll
      for (int nt = 0; nt < 4; nt++)
        acc[mt][nt] = __builtin_amdgcn_mfma_f32_16x16x32_bf16(ajf, yf[nt], acc[mt][nt], 0, 0, 0);
    }

    if (it + 1 < NIT){
      stage((it + 1) & 1);   // other buffer: safe, all waves passed barrier it-1
      __syncthreads();       // buf (it+1) complete before anyone computes it
    }
  }

  // epilogue: C/D row=q*4+v -> j, col=nn -> d. Each atomic instruction:
  // 4 q-groups x 16 consecutive d = contiguous 64B segments (R3-proven free).
#pragma unroll
  for (int mt = 0; mt < 4; mt++){
    const int jbase = j0 + wave * 64 + mt * 16 + q * 4;
#pragma unroll
    for (int nt = 0; nt < 4; nt++){
      const int d = nt * 16 + nn;
#pragma unroll
      for (int v = 0; v < 4; v++)
        atomicAdd(out + (size_t)(jbase + v) * DD + d, acc[mt][nt][v]);
    }
  }
}

extern "C" void kernel_launch(void* const* d_in, const int* in_sizes, int n_in,
                              void* d_out, int out_size, void* d_ws, size_t ws_size,
                              hipStream_t stream) {
  const float* x     = (const float*)d_in[0];
  const float* r     = (const float*)d_in[1];
  const float* A     = (const float*)d_in[2];
  const float* Wobj  = (const float*)d_in[3];
  const float* bobj  = (const float*)d_in[4];
  const float* Wnobj = (const float*)d_in[5];
  const float* bnobj = (const float*)d_in[6];
  const float* Wrel  = (const float*)d_in[7];
  const float* brel  = (const float*)d_in[8];
  const float* Wskip = (const float*)d_in[9];
  const float* bskip = (const float*)d_in[10];
  // d_in[11]/d_in[12] (Wa_w/Wa_b) provably unused: softmax rows sum to 1.

  unsigned short* yT = (unsigned short*)d_ws;     // 1 MB; only ws use

  k_proj<<<dim3(32, 16), 256, 0, stream>>>(x, r, Wobj, bobj, Wnobj, bnobj,
                                           Wrel, brel, Wskip, bskip,
                                           (float*)d_out, yT);
  k_spmm<<<dim3(NN / BN, KSPLIT), 256, 0, stream>>>(A, yT, (float*)d_out);
}

// Round 10
// 409.302 us; speedup vs baseline: 1.2123x; 1.0242x over previous
//
#include <hip/hip_runtime.h>

typedef __attribute__((ext_vector_type(8))) short short8;
typedef __attribute__((ext_vector_type(4))) float f32x4;
typedef __attribute__((ext_vector_type(4))) unsigned int u32x4;   // native vec: OK for nontemporal builtins

#define NN 8192
#define DD 64

// f32 -> bf16 RNE (internal y staging only)
__device__ inline unsigned short f2bf(float f){
  unsigned b = __float_as_uint(f);
  b = (b + 0x7fffu + ((b >> 16) & 1u)) >> 16;
  return (unsigned short)b;
}

// ---------------------------------------------------------------------------
// Confirmed: inputs f32, output f32, absmax 0.5 vs threshold 1.78.
// Algebra: softmax rows sum to 1 -> attn_agg == aggregated; Wa_* unused.
//   out = x@(Wobj+Wskip) + r@Wrel + A^T @ (x@Wnobj + bnobj) + (bobj+brel+bskip)
// A is exactly 0/1 -> f32->bf16 truncation EXACT -> bf16 MFMA for A^T y.
//
// R10 = REVERT to R7, the measured best (407.2 us). Session findings:
//  - dur_us = ~330us fixed harness restore/poison inside the timed window
//    (1GiB ws fill measured 160us @6.7TB/s; A-restore ~85us; rest ~85us)
//    + ~77us of kernels (A-stream floor 43us + proj/out/launch ~15us).
//  - Five structural variants (R3 409.7 / R4 416.2 / R5 414.5 / R7 407.2 /
//    R9 419.2) differ only by traffic/transaction arithmetic.
//  - Atomic law: f32 atomics ~free iff each instruction's lanes cover
//    contiguous 64B segments (R3/R9); 16-line scatter costs ~90us/8.4M (R8).
//  - R9's consolidation (direct-to-d_out) was neutral-to-worse: atomic RMW
//    L2 traffic + scattered k_proj stores offset the saved k_out pass.
// ---------------------------------------------------------------------------

// Kernel 1: accT[d][i] = x@(Wobj+Wskip)+r@Wrel+biases ; yT[d][i]=bf16(x@Wnobj+bnobj)
__global__ __launch_bounds__(256) void k_proj(
    const float* __restrict__ x, const float* __restrict__ r,
    const float* __restrict__ Wobj,  const float* __restrict__ bobj,
    const float* __restrict__ Wnobj, const float* __restrict__ bnobj,
    const float* __restrict__ Wrel,  const float* __restrict__ brel,
    const float* __restrict__ Wskip, const float* __restrict__ bskip,
    float* __restrict__ accT, unsigned short* __restrict__ yT)
{
  const int i  = blockIdx.x * 256 + threadIdx.x;   // row
  const int d0 = blockIdx.y * 4;                   // 4 output dims

  float ay[4] = {0.f,0.f,0.f,0.f}, az[4] = {0.f,0.f,0.f,0.f};
  const float4* xp = (const float4*)(x + (size_t)i * DD);
  const float4* rp = (const float4*)(r + (size_t)i * DD);

#pragma unroll
  for (int kb = 0; kb < 4; kb++){                  // 16 k per chunk
    float xv[16], rv[16];
#pragma unroll
    for (int p = 0; p < 4; p++){
      float4 u = xp[kb*4 + p];
      xv[4*p+0]=u.x; xv[4*p+1]=u.y; xv[4*p+2]=u.z; xv[4*p+3]=u.w;
      float4 v = rp[kb*4 + p];
      rv[4*p+0]=v.x; rv[4*p+1]=v.y; rv[4*p+2]=v.z; rv[4*p+3]=v.w;
    }
#pragma unroll
    for (int kk = 0; kk < 16; kk++){
      const int wb = (kb*16 + kk) * DD + d0;       // uniform -> s_loads
      const float xk = xv[kk], rk = rv[kk];
#pragma unroll
      for (int t = 0; t < 4; t++){
        ay[t] += xk * Wnobj[wb + t];
        az[t] += xk * Wobj [wb + t];
        az[t] += xk * Wskip[wb + t];
        az[t] += rk * Wrel [wb + t];
      }
    }
  }

#pragma unroll
  for (int t = 0; t < 4; t++){
    ay[t] += bnobj[d0 + t];
    az[t] += bobj[d0 + t] + brel[d0 + t] + bskip[d0 + t];
    yT[(size_t)(d0 + t) * NN + i]   = f2bf(ay[t]);   // coalesced
    accT[(size_t)(d0 + t) * NN + i] = az[t];
  }
}

// ---------------------------------------------------------------------------
// Kernel 2: part[kb][d][j] = sum_{k in chunk} yT[d][k]*A[k][j]  (bf16 MFMA)
// BN=256 (1KB A segments/row), 32-k tiles, double-buffered, KSPLIT=16.
// grid (32 jb, 16 kb) = 512 blocks = 2/CU; LDS 42KB (3 blocks/CU capacity).
// XOR-chunk swizzle: B-frag u16 reads and all staging phases <=2-way (free).
// ---------------------------------------------------------------------------
#define BN 256
#define KSPLIT 16
#define KCH (NN / KSPLIT)    // 512
#define KT 32                // k-depth per tile
#define NIT (KCH / KT)       // 16
#define ASZ (KT * BN)        // 8192 elems (16 KB)
#define YPITCH 40            // 32 + 8: rows 80B = 16B-aligned, af reads 2-way
#define YSZ (DD * YPITCH)    // 2560 elems (5 KB)

__global__ __launch_bounds__(256) void k_spmm(
    const float* __restrict__ A,
    const unsigned short* __restrict__ yT,
    float* __restrict__ part)
{
  __shared__ short Alds[2 * ASZ];
  __shared__ short Ylds[2 * YSZ];

  const int tid  = threadIdx.x;
  const int lane = tid & 63;
  const int wave = tid >> 6;
  const int q    = lane >> 4;    // k-quad within fragment
  const int nn   = lane & 15;    // m (A-frag) / n (B-frag, C col) index

  const int j0     = blockIdx.x * BN;
  const int kstart = blockIdx.y * KCH;

  // A staging: rows kr + 4p (p=0..7), cols c4*4 (16B); wave = 64 contiguous lanes
  const int c4 = tid & 63;       // 4-col chunk within 1KB row
  const int kr = tid >> 6;       // 0..3
  // y staging: 64 m-rows x 4 8-k chunks
  const int cY = tid & 3;
  const int m  = tid >> 2;       // 0..63

  const float* ap          = A  + (size_t)(kstart + kr) * NN + j0 + c4 * 4;
  const unsigned short* yp = yT + (size_t)m * NN + kstart + cY * 8;

  u32x4 abuf[8]; uint4 ybuf;
  auto gload = [&](){
#pragma unroll
    for (int p = 0; p < 8; p++)   // nontemporal: A lines are single-use
      abuf[p] = __builtin_nontemporal_load((const u32x4*)(ap + (size_t)p * 4 * NN));
    ybuf = *(const uint4*)yp;
    ap += (size_t)KT * NN;        // next 32-k tile
    yp += KT;
  };
  auto stage = [&](int buf){
    short* Ab = &Alds[buf * ASZ];
    short* Yb = &Ylds[buf * YSZ];
#pragma unroll
    for (int p = 0; p < 8; p++){
      const int kk  = kr + p*4;                    // 0..31
      const int key = 2 * ((kk >> 3) & 3);
      // exact f32->bf16 truncation (A is 0/1), packed two at a time
      unsigned lo = (abuf[p][1] & 0xFFFF0000u) | (abuf[p][0] >> 16);
      unsigned hi = (abuf[p][3] & 0xFFFF0000u) | (abuf[p][2] >> 16);
      *(uint2*)(&Ab[kk * BN + (((c4 >> 1) ^ key) * 8) + (c4 & 1) * 4]) =
          make_uint2(lo, hi);
    }
    *(uint4*)(&Yb[m * YPITCH + cY * 8]) = ybuf;
  };

  f32x4 acc[4][4];
#pragma unroll
  for (int a = 0; a < 4; a++)
#pragma unroll
    for (int b = 0; b < 4; b++)
      acc[a][b] = (f32x4){0.f, 0.f, 0.f, 0.f};

  gload();
  stage(0);
  __syncthreads();

  for (int it = 0; it < NIT; ++it){
    if (it + 1 < NIT) gload();       // in flight across this tile's compute
    const short* Ab = &Alds[(it & 1) * ASZ];
    const short* Yb = &Ylds[(it & 1) * YSZ];

    short8 af[4];
#pragma unroll
    for (int mt = 0; mt < 4; mt++)    // A-frag: yT[m=16mt+nn][k=q*8..q*8+7]
      af[mt] = *(const short8*)(&Yb[(mt*16 + nn) * YPITCH + q*8]);
#pragma unroll
    for (int nt = 0; nt < 4; nt++){
      const int col = wave * 64 + nt * 16 + nn;
      // B-frag: A[k=q*8+jj][col]; chunk swizzle key (k>>3)&3 == q for jj<8
      const short* bp = &Ab[(q*8) * BN + (((col >> 3) ^ (2*q)) * 8) + (col & 7)];
      short8 bf;
#pragma unroll
      for (int jj = 0; jj < 8; jj++) bf[jj] = bp[jj * BN];
#pragma unroll
      for (int mt = 0; mt < 4; mt++)
        acc[mt][nt] = __builtin_amdgcn_mfma_f32_16x16x32_bf16(af[mt], bf, acc[mt][nt], 0, 0, 0);
    }

    if (it + 1 < NIT){
      stage((it + 1) & 1);   // other buffer: safe, all waves passed barrier it-1
      __syncthreads();       // buf (it+1) complete before anyone computes it
    }
  }

  // epilogue: C/D layout col=lane&15, row=q*4+reg; disjoint region, plain stores
  float* pp = part + (size_t)blockIdx.y * DD * NN;
#pragma unroll
  for (int mt = 0; mt < 4; mt++)
#pragma unroll
    for (int nt = 0; nt < 4; nt++)
#pragma unroll
      for (int v = 0; v < 4; v++){
        const int d   = mt * 16 + q * 4 + v;
        const int col = j0 + wave * 64 + nt * 16 + nn;
        pp[(size_t)d * NN + col] = acc[mt][nt][v];
      }
}

// ---------------------------------------------------------------------------
// Kernel 3: out[j][d] = accT[d][j] + sum_kb part[kb][d][j]  (LDS transpose)
// ---------------------------------------------------------------------------
__global__ __launch_bounds__(256) void k_out(
    const float* __restrict__ accT, const float* __restrict__ part,
    float* __restrict__ out)
{
  __shared__ float t[64][33];      // pitch 33: both phases conflict-cheap
  const int tid = threadIdx.x;
  const int jb  = blockIdx.x * 32;

#pragma unroll
  for (int rep = 0; rep < 8; rep++){
    const int d = rep * 8 + (tid >> 5);
    const int j = tid & 31;
    const size_t base = (size_t)d * NN + jb + j;
    float s = accT[base];
#pragma unroll
    for (int kb = 0; kb < KSPLIT; kb++)
      s += __builtin_nontemporal_load(part + (size_t)kb * DD * NN + base);
    t[d][j] = s;
  }
  __syncthreads();
#pragma unroll
  for (int rep = 0; rep < 8; rep++){
    const int j = rep * 4 + (tid >> 6);
    const int d = tid & 63;
    out[(size_t)(jb + j) * DD + d] = t[d][j];
  }
}

extern "C" void kernel_launch(void* const* d_in, const int* in_sizes, int n_in,
                              void* d_out, int out_size, void* d_ws, size_t ws_size,
                              hipStream_t stream) {
  const float* x     = (const float*)d_in[0];
  const float* r     = (const float*)d_in[1];
  const float* A     = (const float*)d_in[2];
  const float* Wobj  = (const float*)d_in[3];
  const float* bobj  = (const float*)d_in[4];
  const float* Wnobj = (const float*)d_in[5];
  const float* bnobj = (const float*)d_in[6];
  const float* Wrel  = (const float*)d_in[7];
  const float* brel  = (const float*)d_in[8];
  const float* Wskip = (const float*)d_in[9];
  const float* bskip = (const float*)d_in[10];
  // d_in[11]/d_in[12] (Wa_w/Wa_b) provably unused: softmax rows sum to 1.

  char* ws = (char*)d_ws;
  float* accT        = (float*)ws;                                  // 2 MB
  unsigned short* yT = (unsigned short*)(ws + (size_t)DD*NN*4);     // 1 MB
  float* part        = (float*)(ws + 3u*1024*1024);                 // 32 MB

  k_proj<<<dim3(32, 16), 256, 0, stream>>>(x, r, Wobj, bobj, Wnobj, bnobj,
                                           Wrel, brel, Wskip, bskip, accT, yT);
  k_spmm<<<dim3(NN / BN, KSPLIT), 256, 0, stream>>>(A, yT, part);
  k_out<<<NN / 32, 256, 0, stream>>>(accT, part, (float*)d_out);
}